// Round 10
// baseline (523.019 us; speedup 1.0000x reference)
//
#include <hip/hip_runtime.h>
#include <hip/hip_bf16.h>

typedef unsigned int uint;
typedef unsigned short ushort;
typedef unsigned long long ull;
typedef __attribute__((ext_vector_type(8))) short short8;
typedef __attribute__((ext_vector_type(4))) float f32x4;

// packed transposed W (bf16), fragment-contiguous: [mat][t][ks][ot][lane][8]
// element = W[t][d][o] with o = ot*16 + (lane&15), d = ks*32 + (lane>>4)*8 + j
#define WP_ELEMS 147456

__device__ __forceinline__ ushort f2bf(float f) {
  uint x = __float_as_uint(f);
  return (ushort)((x + 0x7fffu + ((x >> 16) & 1u)) >> 16);
}
__device__ __forceinline__ uint packbf(float a, float b) {
  return ((uint)f2bf(b) << 16) | (uint)f2bf(a);
}
__device__ __forceinline__ float bflo(uint u) { return __uint_as_float(u << 16); }
__device__ __forceinline__ float bfhi(uint u) { return __uint_as_float(u & 0xffff0000u); }

// ---- setup: W->bf16 pack, et-only score/value tables, node-type count, edge histogram ----
// ktab[et*128+c] = 0.25 * rel_q * rel_k     (sign handled per-edge as a scalar)
// vtab[et*128+c] = rel_v
__global__ __launch_bounds__(256) void setup_kernel(
    const float* __restrict__ wq, const float* __restrict__ wk, const float* __restrict__ wv,
    const float* __restrict__ rq, const float* __restrict__ rk, const float* __restrict__ rv,
    ushort* __restrict__ Wp, float* __restrict__ ktab, float* __restrict__ vtab,
    const int* __restrict__ ntype, int* __restrict__ cnt,
    const int* __restrict__ edst, int* __restrict__ ecnt, int N, int E) {
  int i = blockIdx.x * 256 + threadIdx.x;
  if (i < WP_ELEMS) {
    int j    = i & 7;
    int lane = (i >> 3) & 63;
    int ot   = (i >> 9) & 7;
    int ks   = (i >> 12) & 3;
    int mt   = i >> 14;            // mat*3 + t, 0..8
    int mat  = mt / 3;
    int t    = mt - mat * 3;
    int o = ot * 16 + (lane & 15);
    int d = ks * 32 + (lane >> 4) * 8 + j;
    const float* src = (mat == 0) ? wq : (mat == 1) ? wk : wv;
    Wp[i] = f2bf(src[t * 16384 + d * 128 + o]);
  }
  if (i < 1024) {                  // et (8) x c (128)
    ktab[i] = 0.25f * rq[i] * rk[i];
    vtab[i] = rv[i];
  }
  {                                // node-type count (ballot-aggregated)
    int lane = threadIdx.x & 63;
    int t = (i < N) ? ntype[i] : -1;
#pragma unroll
    for (int tt = 0; tt < 3; ++tt) {
      ull mask = __ballot(t == tt);
      if (mask) {
        int leader = __ffsll((long long)mask) - 1;
        if (lane == leader) atomicAdd(&cnt[tt], __popcll(mask));
      }
    }
  }
  if (i < E) atomicAdd(&ecnt[edst[i]], 1);
}

// fill computes bucket offsets from cnt directly (offs_kernel folded in);
// thread 0 writes off[] to memory for gemm.
__global__ __launch_bounds__(256) void fill_kernel(const int* __restrict__ ntype,
                                                   const int* __restrict__ cnt,
                                                   int* __restrict__ pos,
                                                   int* __restrict__ perm,
                                                   int* __restrict__ pinv,
                                                   int* __restrict__ off, int N) {
  int i = blockIdx.x * 256 + threadIdx.x;
  int lane = threadIdx.x & 63;
  int c0 = cnt[0], c1 = cnt[1];
  int o1 = ((c0 + 63) >> 6) << 6;
  int o2 = o1 + (((c1 + 63) >> 6) << 6);
  if (i == 0) {
    int c2 = cnt[2];
    int o3 = o2 + (((c2 + 63) >> 6) << 6);
    off[0] = 0; off[1] = o1; off[2] = o2; off[3] = o3;
  }
  int t = (i < N) ? ntype[i] : -1;
#pragma unroll
  for (int tt = 0; tt < 3; ++tt) {
    ull mask = __ballot(t == tt);
    if (mask) {
      int leader = __ffsll((long long)mask) - 1;
      int base = 0;
      if (lane == leader) base = atomicAdd(&pos[tt], __popcll(mask));
      base = __shfl(base, leader);
      if (t == tt) {
        int obase = (tt == 0) ? 0 : (tt == 1) ? o1 : o2;
        int rank = __popcll(mask & ((lane == 63) ? 0x7fffffffffffffffull
                                                 : ((1ull << lane) - 1ull)));
        int p = obase + base + rank;
        perm[p] = i;
        pinv[i] = p;
      }
    }
  }
}

// ---------------- MFMA QKV projection (unchanged, measured-stable) ----------------
__global__ __launch_bounds__(256) void gemm_kernel(
    const float* __restrict__ X, const int* __restrict__ perm,
    const int* __restrict__ off, const ushort* __restrict__ Wp,
    const float* __restrict__ bq, const float* __restrict__ bk, const float* __restrict__ bv,
    float* __restrict__ Qp, uint* __restrict__ KVp) {
  __shared__ __align__(16) char smem[33792];   // As (17408B) then reused as tbuf (33792B)
  __shared__ int prow[64];
  ushort* As = (ushort*)smem;                  // pitch 136 -> 2-way LDS only (free)
  float* tbuf = (float*)smem;                  // per-wave 16x132 fp32 tile
  const int tid = threadIdx.x;
  const int base = blockIdx.x * 64;
  const int off1 = off[1], off2 = off[2], off3 = off[3];
  if (base >= off3) return;
  const int t = (base >= off1) + (base >= off2);

  if (tid < 64) prow[tid] = perm[base + tid];
  __syncthreads();
#pragma unroll
  for (int pass = 0; pass < 8; ++pass) {
    int row = pass * 8 + (tid >> 5);
    int dw = tid & 31;                       // float4 index within row
    int p = prow[row];
    uint ux = 0u, uy = 0u;
    if (p >= 0) {
      float4 xv = *(const float4*)(X + (size_t)p * 128 + dw * 4);
      ux = packbf(xv.x, xv.y);
      uy = packbf(xv.z, xv.w);
    }
    uint* s = (uint*)smem + row * 68 + dw * 2;
    s[0] = ux; s[1] = uy;
  }
  __syncthreads();

  const int lane = tid & 63;
  const int w = tid >> 6;
  const int m0 = w * 16;
  const int r = lane & 15;
  const int q = lane >> 4;

  short8 afrag[4];
#pragma unroll
  for (int ks = 0; ks < 4; ++ks)
    afrag[ks] = *(const short8*)(As + (m0 + r) * 136 + ks * 32 + q * 8);
  __syncthreads();     // all waves done reading As; tbuf may overwrite

  float* tw = tbuf + w * 2112;   // 16 rows x pitch 132
  uint4 ksave[4];
#pragma unroll
  for (int mat = 0; mat < 3; ++mat) {
    f32x4 acc[8];
#pragma unroll
    for (int ot = 0; ot < 8; ++ot) acc[ot] = (f32x4){0.f, 0.f, 0.f, 0.f};

    const ushort* wb = Wp + (size_t)(mat * 3 + t) * 16384 + lane * 8;
#pragma unroll
    for (int ks = 0; ks < 4; ++ks) {
      const ushort* wk_ = wb + ks * 4096;
#pragma unroll
      for (int ot = 0; ot < 8; ++ot) {
        short8 b = *(const short8*)(wk_ + ot * 512);
        acc[ot] = __builtin_amdgcn_mfma_f32_16x16x32_bf16(afrag[ks], b, acc[ot], 0, 0, 0);
      }
    }

    const float* bias = (mat == 0) ? bq : (mat == 1) ? bk : bv;
#pragma unroll
    for (int ot = 0; ot < 8; ++ot) {
      float bi = bias[t * 128 + ot * 16 + r];
#pragma unroll
      for (int reg = 0; reg < 4; ++reg)
        tw[(q * 4 + reg) * 132 + ot * 16 + r] = acc[ot][reg] + bi;
    }
    if (mat == 0) {
#pragma unroll
      for (int p = 0; p < 8; ++p) {
        int f = (p * 64 + lane) * 4;
        int row = f >> 7, col = f & 127;
        float4 val = *(const float4*)(tw + row * 132 + col);
        *(float4*)(Qp + (size_t)(base + m0 + row) * 128 + col) = val;
      }
    } else if (mat == 1) {
#pragma unroll
      for (int p = 0; p < 4; ++p) {
        int g = p * 64 + lane;
        int f = g * 8;
        int row = f >> 7, col = f & 127;
        const float* src = tw + row * 132 + col;
        float4 a4 = *(const float4*)(src);
        float4 b4 = *(const float4*)(src + 4);
        uint4 u;
        u.x = packbf(a4.x, a4.y);
        u.y = packbf(a4.z, a4.w);
        u.z = packbf(b4.x, b4.y);
        u.w = packbf(b4.z, b4.w);
        ksave[p] = u;           // K pairs, held in regs across mat=2
      }
    } else {
#pragma unroll
      for (int p = 0; p < 4; ++p) {
        int g = p * 64 + lane;
        int f = g * 8;
        int row = f >> 7, col = f & 127;
        const float* src = tw + row * 132 + col;
        float4 a4 = *(const float4*)(src);
        float4 b4 = *(const float4*)(src + 4);
        uint4 v4;
        v4.x = packbf(a4.x, a4.y);
        v4.y = packbf(a4.z, a4.w);
        v4.z = packbf(b4.x, b4.y);
        v4.w = packbf(b4.z, b4.w);
        uint4 w0, w1;
        w0.x = ksave[p].x; w0.y = v4.x; w0.z = ksave[p].y; w0.w = v4.y;
        w1.x = ksave[p].z; w1.y = v4.z; w1.z = ksave[p].w; w1.w = v4.w;
        uint* dstp = KVp + (size_t)(base + m0 + row) * 128 + col;  // col even
        *(uint4*)(dstp) = w0;
        *(uint4*)(dstp + 4) = w1;
      }
    }
  }
}

// ---------------- CSR build ----------------
__global__ __launch_bounds__(256) void csum_kernel(const int* __restrict__ ecnt,
                                                   int* __restrict__ csum, int N) {
  __shared__ int s[4];
  int basei = blockIdx.x * 1024;
  int tid = threadIdx.x;
  int v = 0;
#pragma unroll
  for (int k = 0; k < 4; ++k) {
    int i = basei + k * 256 + tid;
    if (i < N) v += ecnt[i];
  }
#pragma unroll
  for (int m = 1; m < 64; m <<= 1) v += __shfl_xor(v, m);
  if ((tid & 63) == 0) s[tid >> 6] = v;
  __syncthreads();
  if (tid == 0) csum[blockIdx.x] = s[0] + s[1] + s[2] + s[3];
}

// rowptr with cscan folded in: each block reduces csum[0..bid-1] for its base.
__global__ __launch_bounds__(1024) void rowptr_kernel(const int* __restrict__ ecnt,
                                                      const int* __restrict__ csum,
                                                      int* __restrict__ rowptr,
                                                      int* __restrict__ cursor,
                                                      int N, int E) {
  __shared__ int sd[32];
  __shared__ int sbase;
  int basei = blockIdx.x * 1024;
  int tid = threadIdx.x, lane = tid & 63, w = tid >> 6;

  // phase 1: block-exclusive base = sum csum[0..blockIdx.x-1] (blockIdx.x < 1024)
  int c = (tid < blockIdx.x) ? csum[tid] : 0;
#pragma unroll
  for (int m = 1; m < 64; m <<= 1) c += __shfl_xor(c, m);
  if (lane == 0) sd[w] = c;
  __syncthreads();
  if (tid == 0) {
    int s = 0;
#pragma unroll
    for (int k = 0; k < 16; ++k) s += sd[k];
    sbase = s;
    if (blockIdx.x == 0) rowptr[N] = E;
  }
  __syncthreads();

  // phase 2: intra-block scan (sd reused after sync)
  int i = basei + tid;
  int v = (i < N) ? ecnt[i] : 0;
  int x = v;
#pragma unroll
  for (int d = 1; d < 64; d <<= 1) {
    int t = __shfl_up(x, d);
    if (lane >= d) x += t;
  }
  if (lane == 63) sd[w] = x;
  __syncthreads();
  if (w == 0 && lane < 16) {
    int y = sd[lane];
#pragma unroll
    for (int d = 1; d < 16; d <<= 1) {
      int t = __shfl_up(y, d);
      if (lane >= d) y += t;
    }
    sd[16 + lane] = y;
  }
  __syncthreads();
  int excl = sbase + ((w > 0) ? sd[16 + w - 1] : 0) + (x - v);
  if (i < N) { rowptr[i] = excl; cursor[i] = excl; }
}

// single int2 record: {pinv_src | et<<18 | signbit<<21, bits(phi)} -- one 8B store
__global__ __launch_bounds__(256) void scatter_kernel(
    const int* __restrict__ esrc, const int* __restrict__ edst,
    const int* __restrict__ etype, const int* __restrict__ esign,
    const float* __restrict__ edist,
    const float* __restrict__ p_alpha, const float* __restrict__ p_tau,
    const int* __restrict__ pinv, int* __restrict__ cursor,
    int2* __restrict__ erec, int E) {
  int e = blockIdx.x * 256 + threadIdx.x;
  if (e >= E) return;
  int dst = edst[e];
  int p = atomicAdd(&cursor[dst], 1);
  int et = etype[e], sg = esign[e];
  int sbit = (sg == -1) ? 1 : 0;     // sign_k/sign_v are -1 iff edge_sign == -1
  float parg = fminf(fmaxf(-edist[e] / (p_tau[0] + 1e-9f), -80.f), 0.f);
  int2 r;
  r.x = pinv[esrc[e]] | (et << 18) | (sbit << 21);
  r.y = __float_as_int(p_alpha[0] * __expf(parg));
  erec[p] = r;
}

// ---------------- fused aggregation: 4 dsts per wave, depth-2 kv pipeline ----------------
// 16 lanes per edge (group g=lane>>4), 8 channels per lane (cl=lane&15, c0=cl*8).
// Head = cl>>1 -> single shfl_xor(1) score reduce.
// Depth-2 kv-only register pipeline: stages hold {pk, phi, kv0, kv1} (10 VGPR);
// table/rb loads happen at compute time (8KB tables, L1-hot). Invalid slot = pk<0.
struct St {
  int pk;                   // pinv | et<<18 | sbit<<21, bit31 = invalid
  float phi;
  uint4 kv0, kv1;           // {K,V,K,V} packed pairs, channels c0..c0+7
};

__device__ __forceinline__ St fetchs(
    int e0, int row1, const int2* __restrict__ erec,
    const uint* __restrict__ KVp, int cl) {
  St s;
  int e = (e0 < row1) ? e0 : (row1 - 1);   // clamped: deg>0 guaranteed by caller
  int2 r = erec[e];
  s.pk = r.x | ((e0 < row1) ? 0 : (int)0x80000000);
  s.phi = __int_as_float(r.y);
  const uint* kvb = KVp + (size_t)(r.x & 0x3ffff) * 128 + cl * 8;
  s.kv0 = *(const uint4*)(kvb);
  s.kv1 = *(const uint4*)(kvb + 4);
  return s;
}

__device__ __forceinline__ void computes(
    const St& s, const float* __restrict__ ktab, const float* __restrict__ vtab,
    const float* __restrict__ rb, int cl,
    const float4& q0, const float4& q1, float& z,
    float& a0, float& a1, float& a2, float& a3,
    float& a4, float& a5, float& a6, float& a7) {
  int et = (s.pk >> 18) & 7;
  float sgn = (s.pk & (1 << 21)) ? -1.f : 1.f;
  const float* kb = ktab + et * 128 + cl * 8;
  float4 t0 = *(const float4*)(kb);
  float4 t1 = *(const float4*)(kb + 4);
  const float* vb = vtab + et * 128 + cl * 8;
  float4 v0 = *(const float4*)(vb);
  float4 v1 = *(const float4*)(vb + 4);
  float bias = rb[et * 8 + (cl >> 1)] + s.phi;

  float part = q0.x * (t0.x * bflo(s.kv0.x));
  part = fmaf(q0.y, t0.y * bfhi(s.kv0.x), part);
  part = fmaf(q0.z, t0.z * bflo(s.kv0.z), part);
  part = fmaf(q0.w, t0.w * bfhi(s.kv0.z), part);
  part = fmaf(q1.x, t1.x * bflo(s.kv1.x), part);
  part = fmaf(q1.y, t1.y * bfhi(s.kv1.x), part);
  part = fmaf(q1.z, t1.z * bflo(s.kv1.z), part);
  part = fmaf(q1.w, t1.w * bfhi(s.kv1.z), part);
  part += __shfl_xor(part, 1);             // full 16-ch head dot
  float score = fminf(fmaf(sgn, part, bias), 80.f);
  float es = __expf(score);
  es = (s.pk >= 0) ? es : 0.f;
  z += es;
  float esv = es * sgn;
  a0 = fmaf(esv, v0.x * bflo(s.kv0.y), a0);
  a1 = fmaf(esv, v0.y * bfhi(s.kv0.y), a1);
  a2 = fmaf(esv, v0.z * bflo(s.kv0.w), a2);
  a3 = fmaf(esv, v0.w * bfhi(s.kv0.w), a3);
  a4 = fmaf(esv, v1.x * bflo(s.kv1.y), a4);
  a5 = fmaf(esv, v1.y * bfhi(s.kv1.y), a5);
  a6 = fmaf(esv, v1.z * bflo(s.kv1.w), a6);
  a7 = fmaf(esv, v1.w * bfhi(s.kv1.w), a7);
}

__global__ __launch_bounds__(256) void agg_kernel(
    const float* __restrict__ Qp, const uint* __restrict__ KVp,
    const int* __restrict__ pinv, const int* __restrict__ rowptr,
    const int2* __restrict__ erec,
    const float* __restrict__ rb, const float* __restrict__ ktab,
    const float* __restrict__ vtab,
    const float* __restrict__ X, const int* __restrict__ ntype,
    const float* __restrict__ skip, const float* __restrict__ gamma,
    const float* __restrict__ beta, float* __restrict__ y, int N) {
  const int wslot = blockIdx.x * 4 + (threadIdx.x >> 6);
  const int lane = threadIdx.x & 63;
  const int g = lane >> 4;        // edge slot 0..3
  const int cl = lane & 15;       // channel lane; channels c0..c0+7
  const int c0 = cl * 8;

  for (int ii = 0; ii < 4; ++ii) {
    int dst = wslot * 4 + ii;     // 4 consecutive dsts per wave
    if (dst >= N) return;

    int pq = pinv[dst];
    int row0 = rowptr[dst], row1 = rowptr[dst + 1];
    const float* qb = Qp + (size_t)pq * 128 + c0;
    float4 q0 = *(const float4*)(qb);
    float4 q1 = *(const float4*)(qb + 4);

    float a0 = 0.f, a1 = 0.f, a2 = 0.f, a3 = 0.f;
    float a4 = 0.f, a5 = 0.f, a6 = 0.f, a7 = 0.f;
    float z = 0.f;

    int deg = row1 - row0;
    if (deg > 0) {
      int np = (deg + 3) >> 2;
      St A = fetchs(row0 + g, row1, erec, KVp, cl);
      St B;
      if (np > 1) B = fetchs(row0 + 4 + g, row1, erec, KVp, cl);
      for (int p = 0; p < np; ++p) {
        if (p + 2 < np) {
          St C = fetchs(row0 + (p + 2) * 4 + g, row1, erec, KVp, cl);
          computes(A, ktab, vtab, rb, cl, q0, q1, z, a0, a1, a2, a3, a4, a5, a6, a7);
          A = B; B = C;
        } else if (p + 1 < np) {
          computes(A, ktab, vtab, rb, cl, q0, q1, z, a0, a1, a2, a3, a4, a5, a6, a7);
          A = B;
        } else {
          computes(A, ktab, vtab, rb, cl, q0, q1, z, a0, a1, a2, a3, a4, a5, a6, a7);
        }
      }
    }

    // cross-group reduce (groups differ in lane bits 4,5)
#pragma unroll
    for (int m = 16; m < 64; m <<= 1) {
      a0 += __shfl_xor(a0, m); a1 += __shfl_xor(a1, m);
      a2 += __shfl_xor(a2, m); a3 += __shfl_xor(a3, m);
      a4 += __shfl_xor(a4, m); a5 += __shfl_xor(a5, m);
      a6 += __shfl_xor(a6, m); a7 += __shfl_xor(a7, m);
      z  += __shfl_xor(z, m);
    }

    if (lane < 16) {
      float inv = 1.0f / (z + 1e-9f);
      float o0 = a0 * inv, o1 = a1 * inv, o2 = a2 * inv, o3 = a3 * inv;
      float o4 = a4 * inv, o5 = a5 * inv, o6 = a6 * inv, o7 = a7 * inv;

      int t = ntype[dst];
      float a = 1.0f / (1.0f + __expf(-skip[t]));
      float b = 1.0f - a;
      const float* xb = X + (size_t)dst * 128 + c0;
      float4 x0 = *(const float4*)(xb);
      float4 x1 = *(const float4*)(xb + 4);
      float w0 = a * o0 + b * x0.x, w1 = a * o1 + b * x0.y;
      float w2 = a * o2 + b * x0.z, w3 = a * o3 + b * x0.w;
      float w4 = a * o4 + b * x1.x, w5 = a * o5 + b * x1.y;
      float w6 = a * o6 + b * x1.z, w7 = a * o7 + b * x1.w;

      float sum = w0 + w1 + w2 + w3 + w4 + w5 + w6 + w7;
      float sq = w0 * w0 + w1 * w1 + w2 * w2 + w3 * w3 +
                 w4 * w4 + w5 * w5 + w6 * w6 + w7 * w7;
#pragma unroll
      for (int m = 1; m < 16; m <<= 1) {
        sum += __shfl_xor(sum, m);
        sq  += __shfl_xor(sq, m);
      }
      float mean = sum * (1.0f / 128.0f);
      float var = fmaxf(sq * (1.0f / 128.0f) - mean * mean, 0.0f);
      float rstd = rsqrtf(var + 1e-5f);

      const float* gb = gamma + t * 128 + c0;
      const float* bb2 = beta + t * 128 + c0;
      float4 g0 = *(const float4*)(gb);
      float4 g1 = *(const float4*)(gb + 4);
      float4 be0 = *(const float4*)(bb2);
      float4 be1 = *(const float4*)(bb2 + 4);
      float4 r0, r1;
      r0.x = (w0 - mean) * rstd * g0.x + be0.x;
      r0.y = (w1 - mean) * rstd * g0.y + be0.y;
      r0.z = (w2 - mean) * rstd * g0.z + be0.z;
      r0.w = (w3 - mean) * rstd * g0.w + be0.w;
      r1.x = (w4 - mean) * rstd * g1.x + be1.x;
      r1.y = (w5 - mean) * rstd * g1.y + be1.y;
      r1.z = (w6 - mean) * rstd * g1.z + be1.z;
      r1.w = (w7 - mean) * rstd * g1.w + be1.w;
      float* yb = y + (size_t)dst * 128 + c0;
      *(float4*)(yb) = r0;
      *(float4*)(yb + 4) = r1;
    }
  }
}

extern "C" void kernel_launch(void* const* d_in, const int* in_sizes, int n_in,
                              void* d_out, int out_size, void* d_ws, size_t ws_size,
                              hipStream_t stream) {
  const float* X     = (const float*)d_in[0];
  const int*   ntype = (const int*)d_in[1];
  const int*   eidx  = (const int*)d_in[2];     // [2,E]
  const int*   etype = (const int*)d_in[3];
  const int*   esign = (const int*)d_in[4];
  const float* edist = (const float*)d_in[5];
  const float* wq = (const float*)d_in[6];
  const float* bq = (const float*)d_in[7];
  const float* wk = (const float*)d_in[8];
  const float* bk = (const float*)d_in[9];
  const float* wv = (const float*)d_in[10];
  const float* bv = (const float*)d_in[11];
  const float* rq = (const float*)d_in[12];
  const float* rk = (const float*)d_in[13];
  const float* rv = (const float*)d_in[14];
  const float* rb = (const float*)d_in[15];

  const int N = in_sizes[1];
  const int E = in_sizes[3];
  const int NP = N + 192;          // permuted rows incl. bucket padding
  const int NC = (N + 1023) / 1024;

  float* ws = (float*)d_ws;
  float* Qp   = ws;                               // NP*128 fp32 (permuted rows)
  uint*  KVp  = (uint*)(Qp + (size_t)NP * 128);   // NP*128 uints, interleaved {K_j,V_j}
  float* ktab = (float*)(KVp + (size_t)NP * 128); // 1024
  float* vtab = ktab + 1024;                      // 1024
  ushort* Wp  = (ushort*)(vtab + 1024);           // 147456
  int* cnt    = (int*)(Wp + WP_ELEMS);            // 4
  int* pos    = cnt + 4;                          // 4
  int* ecnt   = pos + 4;                          // N
  int* perm   = ecnt + N;                         // NP
  int* pinv   = perm + NP;                        // N
  int* off    = pinv + N;                         // 4
  int* rowptr = off + 4;                          // N+1
  int* cursor = rowptr + N + 1;                   // N
  int* csum   = cursor + N;                       // 1024
  int2* erec  = (int2*)(csum + 1024);             // E int2 (packed record + phi)

  hipMemsetAsync(cnt, 0, (size_t)(8 + N) * sizeof(int), stream);   // cnt,pos,ecnt
  hipMemsetAsync(perm, 0xFF, (size_t)NP * sizeof(int), stream);

  setup_kernel<<<(E + 255) / 256, 256, 0, stream>>>(
      wq, wk, wv, rq, rk, rv, Wp, ktab, vtab, ntype, cnt, eidx + E, ecnt, N, E);
  fill_kernel<<<(N + 255) / 256, 256, 0, stream>>>(ntype, cnt, pos, perm, pinv, off, N);

  csum_kernel<<<NC, 256, 0, stream>>>(ecnt, csum, N);
  rowptr_kernel<<<NC, 1024, 0, stream>>>(ecnt, csum, rowptr, cursor, N, E);
  scatter_kernel<<<(E + 255) / 256, 256, 0, stream>>>(
      eidx, eidx + E, etype, esign, edist, (const float*)d_in[20], (const float*)d_in[21],
      pinv, cursor, erec, E);

  gemm_kernel<<<(N + 255) / 64, 256, 0, stream>>>(X, perm, off, Wp, bq, bk, bv, Qp, KVp);

  agg_kernel<<<(N + 15) / 16, 256, 0, stream>>>(Qp, KVp, pinv, rowptr, erec,
                                                rb, ktab, vtab, X, ntype,
                                                (const float*)d_in[22], (const float*)d_in[23],
                                                (const float*)d_in[24], (float*)d_out, N);
}

// Round 11
// 476.193 us; speedup vs baseline: 1.0983x; 1.0983x over previous
//
#include <hip/hip_runtime.h>
#include <hip/hip_bf16.h>

typedef unsigned int uint;
typedef unsigned short ushort;
typedef unsigned long long ull;
typedef __attribute__((ext_vector_type(8))) short short8;
typedef __attribute__((ext_vector_type(4))) float f32x4;

// packed transposed W (bf16), fragment-contiguous: [mat][t][ks][ot][lane][8]
// element = W[t][d][o] with o = ot*16 + (lane&15), d = ks*32 + (lane>>4)*8 + j
#define WP_ELEMS 147456

__device__ __forceinline__ ushort f2bf(float f) {
  uint x = __float_as_uint(f);
  return (ushort)((x + 0x7fffu + ((x >> 16) & 1u)) >> 16);
}
__device__ __forceinline__ uint packbf(float a, float b) {
  return ((uint)f2bf(b) << 16) | (uint)f2bf(a);
}
__device__ __forceinline__ float bflo(uint u) { return __uint_as_float(u << 16); }
__device__ __forceinline__ float bfhi(uint u) { return __uint_as_float(u & 0xffff0000u); }

// ---- setup: W->bf16 pack, et-only score/value tables, node-type count, edge histogram ----
// ktab[et*128+c] = 0.25 * rel_q * rel_k     (sign handled per-edge as a scalar)
// vtab[et*128+c] = rel_v
__global__ __launch_bounds__(256) void setup_kernel(
    const float* __restrict__ wq, const float* __restrict__ wk, const float* __restrict__ wv,
    const float* __restrict__ rq, const float* __restrict__ rk, const float* __restrict__ rv,
    ushort* __restrict__ Wp, float* __restrict__ ktab, float* __restrict__ vtab,
    const int* __restrict__ ntype, int* __restrict__ cnt,
    const int* __restrict__ edst, int* __restrict__ ecnt, int N, int E) {
  int i = blockIdx.x * 256 + threadIdx.x;
  if (i < WP_ELEMS) {
    int j    = i & 7;
    int lane = (i >> 3) & 63;
    int ot   = (i >> 9) & 7;
    int ks   = (i >> 12) & 3;
    int mt   = i >> 14;            // mat*3 + t, 0..8
    int mat  = mt / 3;
    int t    = mt - mat * 3;
    int o = ot * 16 + (lane & 15);
    int d = ks * 32 + (lane >> 4) * 8 + j;
    const float* src = (mat == 0) ? wq : (mat == 1) ? wk : wv;
    Wp[i] = f2bf(src[t * 16384 + d * 128 + o]);
  }
  if (i < 1024) {                  // et (8) x c (128)
    ktab[i] = 0.25f * rq[i] * rk[i];
    vtab[i] = rv[i];
  }
  {                                // node-type count (ballot-aggregated)
    int lane = threadIdx.x & 63;
    int t = (i < N) ? ntype[i] : -1;
#pragma unroll
    for (int tt = 0; tt < 3; ++tt) {
      ull mask = __ballot(t == tt);
      if (mask) {
        int leader = __ffsll((long long)mask) - 1;
        if (lane == leader) atomicAdd(&cnt[tt], __popcll(mask));
      }
    }
  }
  if (i < E) atomicAdd(&ecnt[edst[i]], 1);
}

// ---- fc: fill (node-type bucketing, offs folded) || csum (edge-count block sums) ----
__global__ __launch_bounds__(256) void fc_kernel(
    const int* __restrict__ ntype, const int* __restrict__ cnt,
    int* __restrict__ pos, int* __restrict__ perm, int* __restrict__ pinv,
    int* __restrict__ off,
    const int* __restrict__ ecnt, int* __restrict__ csum,
    int N, int fill_blocks) {
  __shared__ int s[4];
  int bid = blockIdx.x;
  if (bid < fill_blocks) {
    int i = bid * 256 + threadIdx.x;
    int lane = threadIdx.x & 63;
    int c0 = cnt[0], c1 = cnt[1];
    int o1 = ((c0 + 63) >> 6) << 6;
    int o2 = o1 + (((c1 + 63) >> 6) << 6);
    if (i == 0) {
      int c2 = cnt[2];
      int o3 = o2 + (((c2 + 63) >> 6) << 6);
      off[0] = 0; off[1] = o1; off[2] = o2; off[3] = o3;
    }
    int t = (i < N) ? ntype[i] : -1;
#pragma unroll
    for (int tt = 0; tt < 3; ++tt) {
      ull mask = __ballot(t == tt);
      if (mask) {
        int leader = __ffsll((long long)mask) - 1;
        int base = 0;
        if (lane == leader) base = atomicAdd(&pos[tt], __popcll(mask));
        base = __shfl(base, leader);
        if (t == tt) {
          int obase = (tt == 0) ? 0 : (tt == 1) ? o1 : o2;
          int rank = __popcll(mask & ((lane == 63) ? 0x7fffffffffffffffull
                                                   : ((1ull << lane) - 1ull)));
          int p = obase + base + rank;
          perm[p] = i;
          pinv[i] = p;
        }
      }
    }
  } else {
    int cb = bid - fill_blocks;
    int basei = cb * 1024;
    int tid = threadIdx.x;
    int v = 0;
#pragma unroll
    for (int k = 0; k < 4; ++k) {
      int i = basei + k * 256 + tid;
      if (i < N) v += ecnt[i];
    }
#pragma unroll
    for (int m = 1; m < 64; m <<= 1) v += __shfl_xor(v, m);
    if ((tid & 63) == 0) s[tid >> 6] = v;
    __syncthreads();
    if (tid == 0) csum[cb] = s[0] + s[1] + s[2] + s[3];
  }
}

// rowptr with cscan folded in: each block reduces csum[0..bid-1] for its base.
__global__ __launch_bounds__(1024) void rowptr_kernel(const int* __restrict__ ecnt,
                                                      const int* __restrict__ csum,
                                                      int* __restrict__ rowptr,
                                                      int* __restrict__ cursor,
                                                      int N, int E) {
  __shared__ int sd[32];
  __shared__ int sbase;
  int basei = blockIdx.x * 1024;
  int tid = threadIdx.x, lane = tid & 63, w = tid >> 6;

  // phase 1: block-exclusive base = sum csum[0..blockIdx.x-1] (blockIdx.x < 1024)
  int c = (tid < blockIdx.x) ? csum[tid] : 0;
#pragma unroll
  for (int m = 1; m < 64; m <<= 1) c += __shfl_xor(c, m);
  if (lane == 0) sd[w] = c;
  __syncthreads();
  if (tid == 0) {
    int s = 0;
#pragma unroll
    for (int k = 0; k < 16; ++k) s += sd[k];
    sbase = s;
    if (blockIdx.x == 0) rowptr[N] = E;
  }
  __syncthreads();

  // phase 2: intra-block scan (sd reused after sync)
  int i = basei + tid;
  int v = (i < N) ? ecnt[i] : 0;
  int x = v;
#pragma unroll
  for (int d = 1; d < 64; d <<= 1) {
    int t = __shfl_up(x, d);
    if (lane >= d) x += t;
  }
  if (lane == 63) sd[w] = x;
  __syncthreads();
  if (w == 0 && lane < 16) {
    int y = sd[lane];
#pragma unroll
    for (int d = 1; d < 16; d <<= 1) {
      int t = __shfl_up(y, d);
      if (lane >= d) y += t;
    }
    sd[16 + lane] = y;
  }
  __syncthreads();
  int excl = sbase + ((w > 0) ? sd[16 + w - 1] : 0) + (x - v);
  if (i < N) { rowptr[i] = excl; cursor[i] = excl; }
}

// ---------------- gemm body (MFMA QKV projection, measured-stable) ----------------
__device__ void gemm_body(
    int bid, const float* __restrict__ X, const int* __restrict__ perm,
    const int* __restrict__ off, const ushort* __restrict__ Wp,
    const float* __restrict__ bq, const float* __restrict__ bk, const float* __restrict__ bv,
    float* __restrict__ Qp, uint* __restrict__ KVp) {
  __shared__ __align__(16) char smem[33792];   // As (17408B) then reused as tbuf (33792B)
  __shared__ int prow[64];
  ushort* As = (ushort*)smem;                  // pitch 136 -> 2-way LDS only (free)
  float* tbuf = (float*)smem;                  // per-wave 16x132 fp32 tile
  const int tid = threadIdx.x;
  const int base = bid * 64;
  const int off1 = off[1], off2 = off[2], off3 = off[3];
  if (base >= off3) return;
  const int t = (base >= off1) + (base >= off2);

  if (tid < 64) prow[tid] = perm[base + tid];
  __syncthreads();
#pragma unroll
  for (int pass = 0; pass < 8; ++pass) {
    int row = pass * 8 + (tid >> 5);
    int dw = tid & 31;                       // float4 index within row
    int p = prow[row];
    uint ux = 0u, uy = 0u;
    if (p >= 0) {
      float4 xv = *(const float4*)(X + (size_t)p * 128 + dw * 4);
      ux = packbf(xv.x, xv.y);
      uy = packbf(xv.z, xv.w);
    }
    uint* s = (uint*)smem + row * 68 + dw * 2;
    s[0] = ux; s[1] = uy;
  }
  __syncthreads();

  const int lane = tid & 63;
  const int w = tid >> 6;
  const int m0 = w * 16;
  const int r = lane & 15;
  const int q = lane >> 4;

  short8 afrag[4];
#pragma unroll
  for (int ks = 0; ks < 4; ++ks)
    afrag[ks] = *(const short8*)(As + (m0 + r) * 136 + ks * 32 + q * 8);
  __syncthreads();     // all waves done reading As; tbuf may overwrite

  float* tw = tbuf + w * 2112;   // 16 rows x pitch 132
  uint4 ksave[4];
#pragma unroll
  for (int mat = 0; mat < 3; ++mat) {
    f32x4 acc[8];
#pragma unroll
    for (int ot = 0; ot < 8; ++ot) acc[ot] = (f32x4){0.f, 0.f, 0.f, 0.f};

    const ushort* wb = Wp + (size_t)(mat * 3 + t) * 16384 + lane * 8;
#pragma unroll
    for (int ks = 0; ks < 4; ++ks) {
      const ushort* wk_ = wb + ks * 4096;
#pragma unroll
      for (int ot = 0; ot < 8; ++ot) {
        short8 b = *(const short8*)(wk_ + ot * 512);
        acc[ot] = __builtin_amdgcn_mfma_f32_16x16x32_bf16(afrag[ks], b, acc[ot], 0, 0, 0);
      }
    }

    const float* bias = (mat == 0) ? bq : (mat == 1) ? bk : bv;
#pragma unroll
    for (int ot = 0; ot < 8; ++ot) {
      float bi = bias[t * 128 + ot * 16 + r];
#pragma unroll
      for (int reg = 0; reg < 4; ++reg)
        tw[(q * 4 + reg) * 132 + ot * 16 + r] = acc[ot][reg] + bi;
    }
    if (mat == 0) {
#pragma unroll
      for (int p = 0; p < 8; ++p) {
        int f = (p * 64 + lane) * 4;
        int row = f >> 7, col = f & 127;
        float4 val = *(const float4*)(tw + row * 132 + col);
        *(float4*)(Qp + (size_t)(base + m0 + row) * 128 + col) = val;
      }
    } else if (mat == 1) {
#pragma unroll
      for (int p = 0; p < 4; ++p) {
        int g = p * 64 + lane;
        int f = g * 8;
        int row = f >> 7, col = f & 127;
        const float* src = tw + row * 132 + col;
        float4 a4 = *(const float4*)(src);
        float4 b4 = *(const float4*)(src + 4);
        uint4 u;
        u.x = packbf(a4.x, a4.y);
        u.y = packbf(a4.z, a4.w);
        u.z = packbf(b4.x, b4.y);
        u.w = packbf(b4.z, b4.w);
        ksave[p] = u;           // K pairs, held in regs across mat=2
      }
    } else {
#pragma unroll
      for (int p = 0; p < 4; ++p) {
        int g = p * 64 + lane;
        int f = g * 8;
        int row = f >> 7, col = f & 127;
        const float* src = tw + row * 132 + col;
        float4 a4 = *(const float4*)(src);
        float4 b4 = *(const float4*)(src + 4);
        uint4 v4;
        v4.x = packbf(a4.x, a4.y);
        v4.y = packbf(a4.z, a4.w);
        v4.z = packbf(b4.x, b4.y);
        v4.w = packbf(b4.z, b4.w);
        uint4 w0, w1;
        w0.x = ksave[p].x; w0.y = v4.x; w0.z = ksave[p].y; w0.w = v4.y;
        w1.x = ksave[p].z; w1.y = v4.z; w1.z = ksave[p].w; w1.w = v4.w;
        uint* dstp = KVp + (size_t)(base + m0 + row) * 128 + col;  // col even
        *(uint4*)(dstp) = w0;
        *(uint4*)(dstp + 4) = w1;
      }
    }
  }
}

// ---- sg: gemm (blocks 0..gemm_blocks-1, dispatched first) || scatter (rest) ----
// Independent kernels merged for co-residency: gemm is latency-bound, scatter is
// atomic-bound; overlapping them hides both.
__global__ __launch_bounds__(256) void sg_kernel(
    const float* __restrict__ X, const int* __restrict__ perm,
    const int* __restrict__ off, const ushort* __restrict__ Wp,
    const float* __restrict__ bq, const float* __restrict__ bk, const float* __restrict__ bv,
    float* __restrict__ Qp, uint* __restrict__ KVp, int gemm_blocks,
    const int* __restrict__ esrc, const int* __restrict__ edst,
    const int* __restrict__ etype, const int* __restrict__ esign,
    const float* __restrict__ edist,
    const float* __restrict__ p_alpha, const float* __restrict__ p_tau,
    const int* __restrict__ pinv, int* __restrict__ cursor,
    int2* __restrict__ erec, int E) {
  int bid = blockIdx.x;
  if (bid < gemm_blocks) {
    gemm_body(bid, X, perm, off, Wp, bq, bk, bv, Qp, KVp);
    return;
  }
  int e = (bid - gemm_blocks) * 256 + threadIdx.x;
  if (e >= E) return;
  int dst = edst[e];
  int p = atomicAdd(&cursor[dst], 1);
  int et = etype[e], sg = esign[e];
  int sbit = (sg == -1) ? 1 : 0;     // sign_k/sign_v are -1 iff edge_sign == -1
  float parg = fminf(fmaxf(-edist[e] / (p_tau[0] + 1e-9f), -80.f), 0.f);
  int2 r;
  r.x = pinv[esrc[e]] | (et << 18) | (sbit << 21);
  r.y = __float_as_int(p_alpha[0] * __expf(parg));
  erec[p] = r;
}

// ---------------- fused aggregation: 4 dsts per wave, 4 edges per pass ----------------
// (exact round-9 form, measured 114.4 us)
// 16 lanes per edge (group g=lane>>4), 8 channels per lane (cl=lane&15, c0=cl*8).
// Head = cl>>1 -> single shfl_xor(1) score reduce. Depth-1 register ping-pong.
struct Pass {
  uint4 kv0, kv1;           // {K,V,K,V} packed pairs, channels c0..c0+7
  float4 t0, t1;            // kt (0.25*rq*rk) for 8 channels
  float4 v0, v1;            // vt (rv) for 8 channels
  float bias;               // rb + phi
  float sgn;                // +-1
  int valid;
};

__device__ __forceinline__ Pass fetchp(
    int e0, int row1, const int2* __restrict__ erec,
    const uint* __restrict__ KVp, const float* __restrict__ ktab,
    const float* __restrict__ vtab, const float* __restrict__ rb, int cl) {
  Pass P;
  P.valid = (e0 < row1);
  int e = P.valid ? e0 : (row1 - 1);   // clamped: always a real record (deg>0 guaranteed)
  int2 r = erec[e];
  int pk = r.x;
  float phi = __int_as_float(r.y);
  int pe = pk & 0x3ffff;
  int et = (pk >> 18) & 7;
  P.sgn = (pk & (1 << 21)) ? -1.f : 1.f;
  const uint* kvb = KVp + (size_t)pe * 128 + cl * 8;
  P.kv0 = *(const uint4*)(kvb);
  P.kv1 = *(const uint4*)(kvb + 4);
  const float* kb = ktab + et * 128 + cl * 8;
  P.t0 = *(const float4*)(kb);
  P.t1 = *(const float4*)(kb + 4);
  const float* vb = vtab + et * 128 + cl * 8;
  P.v0 = *(const float4*)(vb);
  P.v1 = *(const float4*)(vb + 4);
  P.bias = rb[et * 8 + (cl >> 1)] + phi;
  return P;
}

__device__ __forceinline__ void computep(
    const Pass& P, const float4& q0, const float4& q1, float& z,
    float& a0, float& a1, float& a2, float& a3,
    float& a4, float& a5, float& a6, float& a7) {
  float part = q0.x * (P.t0.x * bflo(P.kv0.x));
  part = fmaf(q0.y, P.t0.y * bfhi(P.kv0.x), part);
  part = fmaf(q0.z, P.t0.z * bflo(P.kv0.z), part);
  part = fmaf(q0.w, P.t0.w * bfhi(P.kv0.z), part);
  part = fmaf(q1.x, P.t1.x * bflo(P.kv1.x), part);
  part = fmaf(q1.y, P.t1.y * bfhi(P.kv1.x), part);
  part = fmaf(q1.z, P.t1.z * bflo(P.kv1.z), part);
  part = fmaf(q1.w, P.t1.w * bfhi(P.kv1.z), part);
  part += __shfl_xor(part, 1);             // full 16-ch head dot
  float score = fminf(fmaf(P.sgn, part, P.bias), 80.f);
  float es = __expf(score);
  es = P.valid ? es : 0.f;
  z += es;
  float esv = es * P.sgn;
  a0 = fmaf(esv, P.v0.x * bflo(P.kv0.y), a0);
  a1 = fmaf(esv, P.v0.y * bfhi(P.kv0.y), a1);
  a2 = fmaf(esv, P.v0.z * bflo(P.kv0.w), a2);
  a3 = fmaf(esv, P.v0.w * bfhi(P.kv0.w), a3);
  a4 = fmaf(esv, P.v1.x * bflo(P.kv1.y), a4);
  a5 = fmaf(esv, P.v1.y * bfhi(P.kv1.y), a5);
  a6 = fmaf(esv, P.v1.z * bflo(P.kv1.w), a6);
  a7 = fmaf(esv, P.v1.w * bfhi(P.kv1.w), a7);
}

__global__ __launch_bounds__(256) void agg_kernel(
    const float* __restrict__ Qp, const uint* __restrict__ KVp,
    const int* __restrict__ pinv, const int* __restrict__ rowptr,
    const int2* __restrict__ erec,
    const float* __restrict__ rb, const float* __restrict__ ktab,
    const float* __restrict__ vtab,
    const float* __restrict__ X, const int* __restrict__ ntype,
    const float* __restrict__ skip, const float* __restrict__ gamma,
    const float* __restrict__ beta, float* __restrict__ y, int N) {
  const int wslot = blockIdx.x * 4 + (threadIdx.x >> 6);
  const int lane = threadIdx.x & 63;
  const int g = lane >> 4;        // edge slot 0..3
  const int cl = lane & 15;       // channel lane; channels c0..c0+7
  const int c0 = cl * 8;

  for (int ii = 0; ii < 4; ++ii) {
    int dst = wslot * 4 + ii;     // 4 consecutive dsts per wave
    if (dst >= N) return;

    int pq = pinv[dst];
    int row0 = rowptr[dst], row1 = rowptr[dst + 1];
    const float* qb = Qp + (size_t)pq * 128 + c0;
    float4 q0 = *(const float4*)(qb);
    float4 q1 = *(const float4*)(qb + 4);

    float a0 = 0.f, a1 = 0.f, a2 = 0.f, a3 = 0.f;
    float a4 = 0.f, a5 = 0.f, a6 = 0.f, a7 = 0.f;
    float z = 0.f;

    int deg = row1 - row0;
    if (deg > 0) {
      int np = (deg + 3) >> 2;
      Pass A = fetchp(row0 + g, row1, erec, KVp, ktab, vtab, rb, cl);
      int p = 0;
      while (true) {
        if (p + 1 < np) {
          Pass B = fetchp(row0 + (p + 1) * 4 + g, row1, erec, KVp, ktab, vtab, rb, cl);
          computep(A, q0, q1, z, a0, a1, a2, a3, a4, a5, a6, a7);
          A = B;
          ++p;
        } else {
          computep(A, q0, q1, z, a0, a1, a2, a3, a4, a5, a6, a7);
          break;
        }
      }
    }

    // cross-group reduce (groups differ in lane bits 4,5)
#pragma unroll
    for (int m = 16; m < 64; m <<= 1) {
      a0 += __shfl_xor(a0, m); a1 += __shfl_xor(a1, m);
      a2 += __shfl_xor(a2, m); a3 += __shfl_xor(a3, m);
      a4 += __shfl_xor(a4, m); a5 += __shfl_xor(a5, m);
      a6 += __shfl_xor(a6, m); a7 += __shfl_xor(a7, m);
      z  += __shfl_xor(z, m);
    }

    if (lane < 16) {
      float inv = 1.0f / (z + 1e-9f);
      float o0 = a0 * inv, o1 = a1 * inv, o2 = a2 * inv, o3 = a3 * inv;
      float o4 = a4 * inv, o5 = a5 * inv, o6 = a6 * inv, o7 = a7 * inv;

      int t = ntype[dst];
      float a = 1.0f / (1.0f + __expf(-skip[t]));
      float b = 1.0f - a;
      const float* xb = X + (size_t)dst * 128 + c0;
      float4 x0 = *(const float4*)(xb);
      float4 x1 = *(const float4*)(xb + 4);
      float w0 = a * o0 + b * x0.x, w1 = a * o1 + b * x0.y;
      float w2 = a * o2 + b * x0.z, w3 = a * o3 + b * x0.w;
      float w4 = a * o4 + b * x1.x, w5 = a * o5 + b * x1.y;
      float w6 = a * o6 + b * x1.z, w7 = a * o7 + b * x1.w;

      float sum = w0 + w1 + w2 + w3 + w4 + w5 + w6 + w7;
      float sq = w0 * w0 + w1 * w1 + w2 * w2 + w3 * w3 +
                 w4 * w4 + w5 * w5 + w6 * w6 + w7 * w7;
#pragma unroll
      for (int m = 1; m < 16; m <<= 1) {
        sum += __shfl_xor(sum, m);
        sq  += __shfl_xor(sq, m);
      }
      float mean = sum * (1.0f / 128.0f);
      float var = fmaxf(sq * (1.0f / 128.0f) - mean * mean, 0.0f);
      float rstd = rsqrtf(var + 1e-5f);

      const float* gb = gamma + t * 128 + c0;
      const float* bb2 = beta + t * 128 + c0;
      float4 g0 = *(const float4*)(gb);
      float4 g1 = *(const float4*)(gb + 4);
      float4 be0 = *(const float4*)(bb2);
      float4 be1 = *(const float4*)(bb2 + 4);
      float4 r0, r1;
      r0.x = (w0 - mean) * rstd * g0.x + be0.x;
      r0.y = (w1 - mean) * rstd * g0.y + be0.y;
      r0.z = (w2 - mean) * rstd * g0.z + be0.z;
      r0.w = (w3 - mean) * rstd * g0.w + be0.w;
      r1.x = (w4 - mean) * rstd * g1.x + be1.x;
      r1.y = (w5 - mean) * rstd * g1.y + be1.y;
      r1.z = (w6 - mean) * rstd * g1.z + be1.z;
      r1.w = (w7 - mean) * rstd * g1.w + be1.w;
      float* yb = y + (size_t)dst * 128 + c0;
      *(float4*)(yb) = r0;
      *(float4*)(yb + 4) = r1;
    }
  }
}

extern "C" void kernel_launch(void* const* d_in, const int* in_sizes, int n_in,
                              void* d_out, int out_size, void* d_ws, size_t ws_size,
                              hipStream_t stream) {
  const float* X     = (const float*)d_in[0];
  const int*   ntype = (const int*)d_in[1];
  const int*   eidx  = (const int*)d_in[2];     // [2,E]
  const int*   etype = (const int*)d_in[3];
  const int*   esign = (const int*)d_in[4];
  const float* edist = (const float*)d_in[5];
  const float* wq = (const float*)d_in[6];
  const float* bq = (const float*)d_in[7];
  const float* wk = (const float*)d_in[8];
  const float* bk = (const float*)d_in[9];
  const float* wv = (const float*)d_in[10];
  const float* bv = (const float*)d_in[11];
  const float* rq = (const float*)d_in[12];
  const float* rk = (const float*)d_in[13];
  const float* rv = (const float*)d_in[14];
  const float* rb = (const float*)d_in[15];

  const int N = in_sizes[1];
  const int E = in_sizes[3];
  const int NP = N + 192;          // permuted rows incl. bucket padding
  const int NC = (N + 1023) / 1024;

  float* ws = (float*)d_ws;
  float* Qp   = ws;                               // NP*128 fp32 (permuted rows)
  uint*  KVp  = (uint*)(Qp + (size_t)NP * 128);   // NP*128 uints, interleaved {K_j,V_j}
  float* ktab = (float*)(KVp + (size_t)NP * 128); // 1024
  float* vtab = ktab + 1024;                      // 1024
  ushort* Wp  = (ushort*)(vtab + 1024);           // 147456
  int* cnt    = (int*)(Wp + WP_ELEMS);            // 4
  int* pos    = cnt + 4;                          // 4
  int* ecnt   = pos + 4;                          // N
  int* perm   = ecnt + N;                         // NP
  int* pinv   = perm + NP;                        // N
  int* off    = pinv + N;                         // 4
  int* rowptr = off + 4;                          // N+1
  int* cursor = rowptr + N + 1;                   // N
  int* csum   = cursor + N;                       // 1024
  int2* erec  = (int2*)(csum + 1024);             // E int2 (packed record + phi)

  hipMemsetAsync(cnt, 0, (size_t)(8 + N) * sizeof(int), stream);   // cnt,pos,ecnt
  hipMemsetAsync(perm, 0xFF, (size_t)NP * sizeof(int), stream);

  setup_kernel<<<(E + 255) / 256, 256, 0, stream>>>(
      wq, wk, wv, rq, rk, rv, Wp, ktab, vtab, ntype, cnt, eidx + E, ecnt, N, E);

  const int fill_blocks = (N + 255) / 256;
  fc_kernel<<<fill_blocks + NC, 256, 0, stream>>>(
      ntype, cnt, pos, perm, pinv, off, ecnt, csum, N, fill_blocks);

  rowptr_kernel<<<NC, 1024, 0, stream>>>(ecnt, csum, rowptr, cursor, N, E);

  const int gemm_blocks = (N + 255) / 64;
  const int scat_blocks = (E + 255) / 256;
  sg_kernel<<<gemm_blocks + scat_blocks, 256, 0, stream>>>(
      X, perm, off, Wp, bq, bk, bv, Qp, KVp, gemm_blocks,
      eidx, eidx + E, etype, esign, edist,
      (const float*)d_in[20], (const float*)d_in[21],
      pinv, cursor, erec, E);

  agg_kernel<<<(N + 15) / 16, 256, 0, stream>>>(Qp, KVp, pinv, rowptr, erec,
                                                rb, ktab, vtab, X, ntype,
                                                (const float*)d_in[22], (const float*)d_in[23],
                                                (const float*)d_in[24], (float*)d_out, N);
}